// Round 1
// baseline (1284.322 us; speedup 1.0000x reference)
//
#include <hip/hip_runtime.h>

constexpr int H  = 16;
constexpr int HD = 48;
constexpr int D  = 768;    // H*HD
constexpr int DZ = 128;
constexpr int S  = 1024;
constexpr float EPS = 1e-5f;

__device__ __forceinline__ float sigmoidf_(float x) { return 1.f / (1.f + __expf(-x)); }

// ---------------------------------------------------------------------------
// Tiled f32 GEMM body: C[m][n] = sum_k A[m][k] * W[n][k]  (+bias[n], A gated by
// sigmoid(G) if G != nullptr). BM=BN=64, BK=16, 256 threads, 4x4 micro-tile.
// ---------------------------------------------------------------------------
__device__ __forceinline__ void gemm_tile(const float* __restrict__ A,
                                          const float* __restrict__ G,
                                          const float* __restrict__ W,
                                          const float* __restrict__ bias,
                                          float* __restrict__ C,
                                          const int bm, const int bn,
                                          const int N, const int K) {
  __shared__ float As[16][68];   // [k][m], row stride 68 floats (16B-aligned rows)
  __shared__ float Bs[16][68];   // [k][n]
  const int tid = threadIdx.x;
  const int tx = tid & 15, ty = tid >> 4;
  const int lr = tid >> 2;          // 0..63 tile row
  const int lk = (tid & 3) << 2;    // 0,4,8,12
  float acc[4][4] = {};
  for (int k0 = 0; k0 < K; k0 += 16) {
    float4 a = *reinterpret_cast<const float4*>(A + (size_t)(bm + lr) * K + (k0 + lk));
    if (G) {
      const float4 g = *reinterpret_cast<const float4*>(G + (size_t)(bm + lr) * K + (k0 + lk));
      a.x *= sigmoidf_(g.x); a.y *= sigmoidf_(g.y);
      a.z *= sigmoidf_(g.z); a.w *= sigmoidf_(g.w);
    }
    const float4 b = *reinterpret_cast<const float4*>(W + (size_t)(bn + lr) * K + (k0 + lk));
    As[lk + 0][lr] = a.x; As[lk + 1][lr] = a.y; As[lk + 2][lr] = a.z; As[lk + 3][lr] = a.w;
    Bs[lk + 0][lr] = b.x; Bs[lk + 1][lr] = b.y; Bs[lk + 2][lr] = b.z; Bs[lk + 3][lr] = b.w;
    __syncthreads();
#pragma unroll
    for (int k = 0; k < 16; ++k) {
      const float4 av = *reinterpret_cast<const float4*>(&As[k][ty << 2]);
      const float4 bv = *reinterpret_cast<const float4*>(&Bs[k][tx << 2]);
      const float am[4] = {av.x, av.y, av.z, av.w};
      const float bb[4] = {bv.x, bv.y, bv.z, bv.w};
#pragma unroll
      for (int i = 0; i < 4; ++i)
#pragma unroll
        for (int j = 0; j < 4; ++j) acc[i][j] += am[i] * bb[j];
    }
    __syncthreads();
  }
  float4 badd = make_float4(0.f, 0.f, 0.f, 0.f);
  if (bias) badd = *reinterpret_cast<const float4*>(bias + bn + (tx << 2));
#pragma unroll
  for (int i = 0; i < 4; ++i) {
    const int m = bm + (ty << 2) + i;
    float4 r;
    r.x = acc[i][0] + badd.x; r.y = acc[i][1] + badd.y;
    r.z = acc[i][2] + badd.z; r.w = acc[i][3] + badd.w;
    *reinterpret_cast<float4*>(C + (size_t)m * N + bn + (tx << 2)) = r;
  }
}

// Fused q/k/v/g projection: grid.x selects weight (4 x D/64), grid.y = S/64.
__global__ __launch_bounds__(256)
void qkvg_kernel(const float* __restrict__ s, const float* __restrict__ Wq,
                 const float* __restrict__ bq, const float* __restrict__ Wk,
                 const float* __restrict__ Wv, const float* __restrict__ Wg,
                 float* __restrict__ out) {
  const int nb = D / 64;
  const int wsel = blockIdx.x / nb;
  const int bn = (blockIdx.x % nb) * 64;
  const int bm = blockIdx.y * 64;
  const float* W = (wsel == 0) ? Wq : (wsel == 1) ? Wk : (wsel == 2) ? Wv : Wg;
  const float* bias = (wsel == 0) ? bq : nullptr;
  float* C = out + (size_t)wsel * S * D;
  gemm_tile(s, nullptr, W, bias, C, bm, bn, D, D);
}

// Gated output projection: out = (o * sigmoid(g)) @ Wo^T
__global__ __launch_bounds__(256)
void outproj_kernel(const float* __restrict__ o, const float* __restrict__ g,
                    const float* __restrict__ Wo, float* __restrict__ out) {
  gemm_tile(o, g, Wo, nullptr, out, blockIdx.y * 64, blockIdx.x * 64, D, D);
}

// ---------------------------------------------------------------------------
// Pair bias: bias[h][s][t] = LN(z[s,t,:]) . Wz[h,:]
// LN folded algebraically: out[h] = inv*(dot(z, w*Wz[h]) - mu*S1[h]) + S2[h].
// Block = 128 threads, 128 (s,t) pairs; z rows staged in LDS (pad+1 -> no bank
// conflicts: bank = (row+c)%32, 2 lanes/bank).
// ---------------------------------------------------------------------------
__global__ __launch_bounds__(128)
void pair_bias_kernel(const float* __restrict__ z, const float* __restrict__ ln_w,
                      const float* __restrict__ ln_b, const float* __restrict__ Wz,
                      float* __restrict__ bias_out) {
  __shared__ float zs[128][DZ + 1];   // 66 KB
  __shared__ float WzW[16][DZ];       // 8 KB: ln_w[c]*Wz[h][c]
  __shared__ float S1s[16], S2s[16];
  const int tid = threadIdx.x;

  for (int e = tid; e < 16 * DZ; e += 128)
    WzW[e >> 7][e & 127] = Wz[e] * ln_w[e & 127];
  __syncthreads();
  if (tid < 16) {
    float s1 = 0.f, s2 = 0.f;
    for (int c = 0; c < DZ; ++c) {
      s1 += WzW[tid][c];
      s2 += ln_b[c] * Wz[tid * DZ + c];
    }
    S1s[tid] = s1; S2s[tid] = s2;
  }

  // stage 128 pair-rows (128*128 floats) coalesced
  const size_t base = (size_t)blockIdx.x * 128 * DZ;
#pragma unroll
  for (int i = 0; i < 32; ++i) {
    const int f4 = i * 128 + tid;       // float4 index; 32 float4 per row
    const int r = f4 >> 5;
    const int c = (f4 & 31) << 2;
    const float4 v = *reinterpret_cast<const float4*>(z + base + (size_t)f4 * 4);
    zs[r][c] = v.x; zs[r][c + 1] = v.y; zs[r][c + 2] = v.z; zs[r][c + 3] = v.w;
  }
  __syncthreads();

  float acc[16] = {};
  float s1 = 0.f, s2 = 0.f;
#pragma unroll 4
  for (int c0 = 0; c0 < DZ; c0 += 4) {
    const float z0 = zs[tid][c0 + 0], z1 = zs[tid][c0 + 1];
    const float z2 = zs[tid][c0 + 2], z3 = zs[tid][c0 + 3];
    s1 += z0 + z1 + z2 + z3;
    s2 += z0 * z0 + z1 * z1 + z2 * z2 + z3 * z3;
#pragma unroll
    for (int hh = 0; hh < 16; ++hh) {
      const float4 w = *reinterpret_cast<const float4*>(&WzW[hh][c0]);
      acc[hh] += z0 * w.x + z1 * w.y + z2 * w.z + z3 * w.w;
    }
  }
  const float mu = s1 * (1.f / DZ);
  const float var = s2 * (1.f / DZ) - mu * mu;
  const float inv = rsqrtf(var + EPS);
  const size_t p = (size_t)blockIdx.x * 128 + tid;   // = s*S + t
#pragma unroll
  for (int hh = 0; hh < 16; ++hh)
    bias_out[(size_t)hh * S * S + p] = inv * (acc[hh] - mu * S1s[hh]) + S2s[hh];
}

// ---------------------------------------------------------------------------
// Attention: one wave per (h, s) row. Scores row (1024) = 16 regs/lane.
// ---------------------------------------------------------------------------
__global__ __launch_bounds__(256)
void attn_kernel(const float* __restrict__ q_ws, const float* __restrict__ k_ws,
                 const float* __restrict__ v_ws, const float* __restrict__ bias,
                 float* __restrict__ o_ws) {
  const int lane = threadIdx.x & 63;
  const int wave = threadIdx.x >> 6;
  const int row = blockIdx.x * 4 + wave;   // 4 waves/block, grid = H*S/4
  const int h = row >> 10;
  const int sq = row & (S - 1);
  const float scale = 0.14433756729740643f;  // 1/sqrt(48)

  const float* qp = q_ws + (size_t)sq * D + h * HD;
  float4 qv[12];
#pragma unroll
  for (int j = 0; j < 12; ++j) {
    qv[j] = *reinterpret_cast<const float4*>(qp + 4 * j);
    qv[j].x *= scale; qv[j].y *= scale; qv[j].z *= scale; qv[j].w *= scale;
  }

  const float* bp = bias + ((size_t)h * S + sq) * S;
  float sc[16];
#pragma unroll
  for (int i = 0; i < 16; ++i) {
    const int t = lane + (i << 6);
    const float* kp = k_ws + (size_t)t * D + h * HD;
    float a = bp[t];
#pragma unroll
    for (int j = 0; j < 12; ++j) {
      const float4 kv = *reinterpret_cast<const float4*>(kp + 4 * j);
      a += qv[j].x * kv.x + qv[j].y * kv.y + qv[j].z * kv.z + qv[j].w * kv.w;
    }
    sc[i] = a;
  }

  float m = sc[0];
#pragma unroll
  for (int i = 1; i < 16; ++i) m = fmaxf(m, sc[i]);
#pragma unroll
  for (int off = 32; off >= 1; off >>= 1) m = fmaxf(m, __shfl_xor(m, off));
  float l = 0.f;
#pragma unroll
  for (int i = 0; i < 16; ++i) { sc[i] = __expf(sc[i] - m); l += sc[i]; }
#pragma unroll
  for (int off = 32; off >= 1; off >>= 1) l += __shfl_xor(l, off);
  const float rl = 1.f / l;
#pragma unroll
  for (int i = 0; i < 16; ++i) sc[i] *= rl;

  float o[48] = {};
#pragma unroll
  for (int i = 0; i < 16; ++i) {
    const int t = lane + (i << 6);
    const float* vp = v_ws + (size_t)t * D + h * HD;
    const float a = sc[i];
#pragma unroll
    for (int j = 0; j < 12; ++j) {
      const float4 vv = *reinterpret_cast<const float4*>(vp + 4 * j);
      o[4 * j + 0] += a * vv.x; o[4 * j + 1] += a * vv.y;
      o[4 * j + 2] += a * vv.z; o[4 * j + 3] += a * vv.w;
    }
  }
#pragma unroll
  for (int d = 0; d < 48; ++d) {
#pragma unroll
    for (int off = 32; off >= 1; off >>= 1) o[d] += __shfl_xor(o[d], off);
  }
  if (lane == 0) {
    float* op = o_ws + (size_t)sq * D + h * HD;
#pragma unroll
    for (int j = 0; j < 12; ++j) {
      *reinterpret_cast<float4*>(op + 4 * j) =
          make_float4(o[4 * j], o[4 * j + 1], o[4 * j + 2], o[4 * j + 3]);
    }
  }
}

extern "C" void kernel_launch(void* const* d_in, const int* in_sizes, int n_in,
                              void* d_out, int out_size, void* d_ws, size_t ws_size,
                              hipStream_t stream) {
  const float* s    = (const float*)d_in[0];
  const float* z    = (const float*)d_in[1];
  const float* Wq   = (const float*)d_in[2];
  const float* bq   = (const float*)d_in[3];
  const float* Wk   = (const float*)d_in[4];
  const float* Wv   = (const float*)d_in[5];
  const float* Wg   = (const float*)d_in[6];
  const float* ln_w = (const float*)d_in[7];
  const float* ln_b = (const float*)d_in[8];
  const float* Wz   = (const float*)d_in[9];
  const float* Wo   = (const float*)d_in[10];
  float* out = (float*)d_out;

  // workspace layout (floats): q,k,v,g,o = 5 * S*D; bias = H*S*S  => ~79 MiB
  float* q_ws    = (float*)d_ws;
  float* k_ws    = q_ws + (size_t)S * D;
  float* v_ws    = k_ws + (size_t)S * D;
  float* g_ws    = v_ws + (size_t)S * D;
  float* o_ws    = g_ws + (size_t)S * D;
  float* bias_ws = o_ws + (size_t)S * D;

  // 1) fused QKVG projections
  qkvg_kernel<<<dim3(4 * (D / 64), S / 64), 256, 0, stream>>>(s, Wq, bq, Wk, Wv, Wg, q_ws);
  // 2) pair bias (LN folded)
  pair_bias_kernel<<<dim3((S * S) / 128), 128, 0, stream>>>(z, ln_w, ln_b, Wz, bias_ws);
  // 3) attention
  attn_kernel<<<dim3(H * S / 4), 256, 0, stream>>>(q_ws, k_ws, v_ws, bias_ws, o_ws);
  // 4) gate + output projection
  outproj_kernel<<<dim3(D / 64, S / 64), 256, 0, stream>>>(o_ws, g_ws, Wo, out);
}

// Round 2
// 666.014 us; speedup vs baseline: 1.9284x; 1.9284x over previous
//
#include <hip/hip_runtime.h>

constexpr int H  = 16;
constexpr int HD = 48;
constexpr int D  = 768;    // H*HD
constexpr int DZ = 128;
constexpr int S  = 1024;
constexpr float EPS = 1e-5f;

__device__ __forceinline__ float sigmoidf_(float x) { return 1.f / (1.f + __expf(-x)); }

// ---------------------------------------------------------------------------
// Tiled f32 GEMM body: C[m][n] = sum_k A[m][k] * W[n][k]  (+bias[n], A gated by
// sigmoid(G) if G != nullptr). BM=BN=64, BK=16, 256 threads, 4x4 micro-tile.
// ---------------------------------------------------------------------------
__device__ __forceinline__ void gemm_tile(const float* __restrict__ A,
                                          const float* __restrict__ G,
                                          const float* __restrict__ W,
                                          const float* __restrict__ bias,
                                          float* __restrict__ C,
                                          const int bm, const int bn,
                                          const int N, const int K) {
  __shared__ float As[16][68];   // [k][m], row stride 68 floats (16B-aligned rows)
  __shared__ float Bs[16][68];   // [k][n]
  const int tid = threadIdx.x;
  const int tx = tid & 15, ty = tid >> 4;
  const int lr = tid >> 2;          // 0..63 tile row
  const int lk = (tid & 3) << 2;    // 0,4,8,12
  float acc[4][4] = {};
  for (int k0 = 0; k0 < K; k0 += 16) {
    float4 a = *reinterpret_cast<const float4*>(A + (size_t)(bm + lr) * K + (k0 + lk));
    if (G) {
      const float4 g = *reinterpret_cast<const float4*>(G + (size_t)(bm + lr) * K + (k0 + lk));
      a.x *= sigmoidf_(g.x); a.y *= sigmoidf_(g.y);
      a.z *= sigmoidf_(g.z); a.w *= sigmoidf_(g.w);
    }
    const float4 b = *reinterpret_cast<const float4*>(W + (size_t)(bn + lr) * K + (k0 + lk));
    As[lk + 0][lr] = a.x; As[lk + 1][lr] = a.y; As[lk + 2][lr] = a.z; As[lk + 3][lr] = a.w;
    Bs[lk + 0][lr] = b.x; Bs[lk + 1][lr] = b.y; Bs[lk + 2][lr] = b.z; Bs[lk + 3][lr] = b.w;
    __syncthreads();
#pragma unroll
    for (int k = 0; k < 16; ++k) {
      const float4 av = *reinterpret_cast<const float4*>(&As[k][ty << 2]);
      const float4 bv = *reinterpret_cast<const float4*>(&Bs[k][tx << 2]);
      const float am[4] = {av.x, av.y, av.z, av.w};
      const float bb[4] = {bv.x, bv.y, bv.z, bv.w};
#pragma unroll
      for (int i = 0; i < 4; ++i)
#pragma unroll
        for (int j = 0; j < 4; ++j) acc[i][j] += am[i] * bb[j];
    }
    __syncthreads();
  }
  float4 badd = make_float4(0.f, 0.f, 0.f, 0.f);
  if (bias) badd = *reinterpret_cast<const float4*>(bias + bn + (tx << 2));
#pragma unroll
  for (int i = 0; i < 4; ++i) {
    const int m = bm + (ty << 2) + i;
    float4 r;
    r.x = acc[i][0] + badd.x; r.y = acc[i][1] + badd.y;
    r.z = acc[i][2] + badd.z; r.w = acc[i][3] + badd.w;
    *reinterpret_cast<float4*>(C + (size_t)m * N + bn + (tx << 2)) = r;
  }
}

// Fused q/k/v/g projection: grid.x selects weight (4 x D/64), grid.y = S/64.
__global__ __launch_bounds__(256)
void qkvg_kernel(const float* __restrict__ s, const float* __restrict__ Wq,
                 const float* __restrict__ bq, const float* __restrict__ Wk,
                 const float* __restrict__ Wv, const float* __restrict__ Wg,
                 float* __restrict__ out) {
  const int nb = D / 64;
  const int wsel = blockIdx.x / nb;
  const int bn = (blockIdx.x % nb) * 64;
  const int bm = blockIdx.y * 64;
  const float* W = (wsel == 0) ? Wq : (wsel == 1) ? Wk : (wsel == 2) ? Wv : Wg;
  const float* bias = (wsel == 0) ? bq : nullptr;
  float* C = out + (size_t)wsel * S * D;
  gemm_tile(s, nullptr, W, bias, C, bm, bn, D, D);
}

// Gated output projection: out = (o * sigmoid(g)) @ Wo^T
__global__ __launch_bounds__(256)
void outproj_kernel(const float* __restrict__ o, const float* __restrict__ g,
                    const float* __restrict__ Wo, float* __restrict__ out) {
  gemm_tile(o, g, Wo, nullptr, out, blockIdx.y * 64, blockIdx.x * 64, D, D);
}

// ---------------------------------------------------------------------------
// Pair bias: bias[h][s][t] = LN(z[s,t,:]) . Wz[h,:]
// LN folded algebraically: out[h] = inv*(dot(z, w*Wz[h]) - mu*S1[h]) + S2[h].
// ---------------------------------------------------------------------------
__global__ __launch_bounds__(128)
void pair_bias_kernel(const float* __restrict__ z, const float* __restrict__ ln_w,
                      const float* __restrict__ ln_b, const float* __restrict__ Wz,
                      float* __restrict__ bias_out) {
  __shared__ float zs[128][DZ + 1];   // 66 KB
  __shared__ float WzW[16][DZ];       // 8 KB: ln_w[c]*Wz[h][c]
  __shared__ float S1s[16], S2s[16];
  const int tid = threadIdx.x;

  for (int e = tid; e < 16 * DZ; e += 128)
    WzW[e >> 7][e & 127] = Wz[e] * ln_w[e & 127];
  __syncthreads();
  if (tid < 16) {
    float s1 = 0.f, s2 = 0.f;
    for (int c = 0; c < DZ; ++c) {
      s1 += WzW[tid][c];
      s2 += ln_b[c] * Wz[tid * DZ + c];
    }
    S1s[tid] = s1; S2s[tid] = s2;
  }

  // stage 128 pair-rows (128*128 floats) coalesced
  const size_t base = (size_t)blockIdx.x * 128 * DZ;
#pragma unroll
  for (int i = 0; i < 32; ++i) {
    const int f4 = i * 128 + tid;       // float4 index; 32 float4 per row
    const int r = f4 >> 5;
    const int c = (f4 & 31) << 2;
    const float4 v = *reinterpret_cast<const float4*>(z + base + (size_t)f4 * 4);
    zs[r][c] = v.x; zs[r][c + 1] = v.y; zs[r][c + 2] = v.z; zs[r][c + 3] = v.w;
  }
  __syncthreads();

  float acc[16] = {};
  float s1 = 0.f, s2 = 0.f;
#pragma unroll 4
  for (int c0 = 0; c0 < DZ; c0 += 4) {
    const float z0 = zs[tid][c0 + 0], z1 = zs[tid][c0 + 1];
    const float z2 = zs[tid][c0 + 2], z3 = zs[tid][c0 + 3];
    s1 += z0 + z1 + z2 + z3;
    s2 += z0 * z0 + z1 * z1 + z2 * z2 + z3 * z3;
#pragma unroll
    for (int hh = 0; hh < 16; ++hh) {
      const float4 w = *reinterpret_cast<const float4*>(&WzW[hh][c0]);
      acc[hh] += z0 * w.x + z1 * w.y + z2 * w.z + z3 * w.w;
    }
  }
  const float mu = s1 * (1.f / DZ);
  const float var = s2 * (1.f / DZ) - mu * mu;
  const float inv = rsqrtf(var + EPS);
  const size_t p = (size_t)blockIdx.x * 128 + tid;   // = s*S + t
#pragma unroll
  for (int hh = 0; hh < 16; ++hh)
    bias_out[(size_t)hh * S * S + p] = inv * (acc[hh] - mu * S1s[hh]) + S2s[hh];
}

// ---------------------------------------------------------------------------
// Flash-style attention. Block = (head h, 64 query rows), 256 threads (16x16).
// Online softmax over 16 K/V tiles of 64. All operand reads from LDS with
// float4 vectors; K rows padded to 52 floats, V transposed [48][68], P [64][68]
// (all pads chosen so same-instr lanes spread >=16 banks; 2-way = free).
// ---------------------------------------------------------------------------
__global__ __launch_bounds__(256)
void attn_kernel(const float* __restrict__ q_ws, const float* __restrict__ k_ws,
                 const float* __restrict__ v_ws, const float* __restrict__ bias,
                 float* __restrict__ o_ws) {
  __shared__ float Qs[64][52];   // query rows (scaled), padded
  __shared__ float Ks[64][52];   // key rows, padded
  __shared__ float Vt[48][68];   // V transposed [d][t]
  __shared__ float Ps[64][68];   // probabilities tile

  const int tid = threadIdx.x;
  const int tx = tid & 15, ty = tid >> 4;
  const int h  = blockIdx.x >> 4;
  const int q0 = (blockIdx.x & 15) << 6;
  const float scale = 0.14433756729740643f;  // 1/sqrt(48)

  // stage Q (scaled): 64 rows x 12 float4
#pragma unroll
  for (int i = 0; i < 3; ++i) {
    const int f4 = tid + i * 256;
    const int r = f4 / 12, c4 = f4 % 12;
    float4 v = *reinterpret_cast<const float4*>(q_ws + (size_t)(q0 + r) * D + h * HD + c4 * 4);
    v.x *= scale; v.y *= scale; v.z *= scale; v.w *= scale;
    *reinterpret_cast<float4*>(&Qs[r][c4 * 4]) = v;
  }

  float m[4], l[4] = {0.f, 0.f, 0.f, 0.f};
  float acc[4][3] = {};
#pragma unroll
  for (int i = 0; i < 4; ++i) m[i] = -1e30f;

  for (int t0 = 0; t0 < S; t0 += 64) {
    // stage K tile (rows) and V tile (transposed)
#pragma unroll
    for (int i = 0; i < 3; ++i) {
      const int f4 = tid + i * 256;
      const int r = f4 / 12, c4 = f4 % 12;
      const float4 kv = *reinterpret_cast<const float4*>(k_ws + (size_t)(t0 + r) * D + h * HD + c4 * 4);
      *reinterpret_cast<float4*>(&Ks[r][c4 * 4]) = kv;
      const float4 vv = *reinterpret_cast<const float4*>(v_ws + (size_t)(t0 + r) * D + h * HD + c4 * 4);
      Vt[c4 * 4 + 0][r] = vv.x; Vt[c4 * 4 + 1][r] = vv.y;
      Vt[c4 * 4 + 2][r] = vv.z; Vt[c4 * 4 + 3][r] = vv.w;
    }
    __syncthreads();

    // S-tile: rows 4ty+i, cols 4tx+j, init from bias
    float s4[4][4];
#pragma unroll
    for (int i = 0; i < 4; ++i) {
      const float4 b4 = *reinterpret_cast<const float4*>(
          bias + ((size_t)h * S + (q0 + 4 * ty + i)) * S + t0 + 4 * tx);
      s4[i][0] = b4.x; s4[i][1] = b4.y; s4[i][2] = b4.z; s4[i][3] = b4.w;
    }
#pragma unroll
    for (int k4 = 0; k4 < 12; ++k4) {
      float4 qv[4], kv[4];
#pragma unroll
      for (int i = 0; i < 4; ++i) qv[i] = *reinterpret_cast<const float4*>(&Qs[4 * ty + i][k4 * 4]);
#pragma unroll
      for (int j = 0; j < 4; ++j) kv[j] = *reinterpret_cast<const float4*>(&Ks[4 * tx + j][k4 * 4]);
#pragma unroll
      for (int i = 0; i < 4; ++i)
#pragma unroll
        for (int j = 0; j < 4; ++j)
          s4[i][j] += qv[i].x * kv[j].x + qv[i].y * kv[j].y +
                      qv[i].z * kv[j].z + qv[i].w * kv[j].w;
    }

    // online softmax (row groups = 16 tx lanes; shfl_xor stays in-group)
#pragma unroll
    for (int i = 0; i < 4; ++i) {
      float tmax = fmaxf(fmaxf(s4[i][0], s4[i][1]), fmaxf(s4[i][2], s4[i][3]));
#pragma unroll
      for (int off = 8; off >= 1; off >>= 1) tmax = fmaxf(tmax, __shfl_xor(tmax, off));
      const float mn = fmaxf(m[i], tmax);
      const float fac = __expf(m[i] - mn);
      float p0 = __expf(s4[i][0] - mn), p1 = __expf(s4[i][1] - mn);
      float p2 = __expf(s4[i][2] - mn), p3 = __expf(s4[i][3] - mn);
      l[i] = l[i] * fac + (p0 + p1 + p2 + p3);   // per-thread partial sum
      acc[i][0] *= fac; acc[i][1] *= fac; acc[i][2] *= fac;
      m[i] = mn;
      *reinterpret_cast<float4*>(&Ps[4 * ty + i][4 * tx]) = make_float4(p0, p1, p2, p3);
    }
    __syncthreads();

    // PV: rows 4ty+i, dims 3tx+j, vectorized over t-quads
#pragma unroll
    for (int t4 = 0; t4 < 16; ++t4) {
      float4 pv[4], vv[3];
#pragma unroll
      for (int i = 0; i < 4; ++i) pv[i] = *reinterpret_cast<const float4*>(&Ps[4 * ty + i][4 * t4]);
#pragma unroll
      for (int j = 0; j < 3; ++j) vv[j] = *reinterpret_cast<const float4*>(&Vt[3 * tx + j][4 * t4]);
#pragma unroll
      for (int i = 0; i < 4; ++i)
#pragma unroll
        for (int j = 0; j < 3; ++j)
          acc[i][j] += pv[i].x * vv[j].x + pv[i].y * vv[j].y +
                       pv[i].z * vv[j].z + pv[i].w * vv[j].w;
    }
    __syncthreads();
  }

  // finalize: full row sum of l across tx group, normalize, write
#pragma unroll
  for (int i = 0; i < 4; ++i) {
    float lt = l[i];
#pragma unroll
    for (int off = 8; off >= 1; off >>= 1) lt += __shfl_xor(lt, off);
    const float rl = 1.f / lt;
    float* op = o_ws + (size_t)(q0 + 4 * ty + i) * D + h * HD;
#pragma unroll
    for (int j = 0; j < 3; ++j) op[3 * tx + j] = acc[i][j] * rl;
  }
}

extern "C" void kernel_launch(void* const* d_in, const int* in_sizes, int n_in,
                              void* d_out, int out_size, void* d_ws, size_t ws_size,
                              hipStream_t stream) {
  const float* s    = (const float*)d_in[0];
  const float* z    = (const float*)d_in[1];
  const float* Wq   = (const float*)d_in[2];
  const float* bq   = (const float*)d_in[3];
  const float* Wk   = (const float*)d_in[4];
  const float* Wv   = (const float*)d_in[5];
  const float* Wg   = (const float*)d_in[6];
  const float* ln_w = (const float*)d_in[7];
  const float* ln_b = (const float*)d_in[8];
  const float* Wz   = (const float*)d_in[9];
  const float* Wo   = (const float*)d_in[10];
  float* out = (float*)d_out;

  // workspace layout (floats): q,k,v,g,o = 5 * S*D; bias = H*S*S  => ~79 MiB
  float* q_ws    = (float*)d_ws;
  float* k_ws    = q_ws + (size_t)S * D;
  float* v_ws    = k_ws + (size_t)S * D;
  float* g_ws    = v_ws + (size_t)S * D;
  float* o_ws    = g_ws + (size_t)S * D;
  float* bias_ws = o_ws + (size_t)S * D;

  // 1) fused QKVG projections
  qkvg_kernel<<<dim3(4 * (D / 64), S / 64), 256, 0, stream>>>(s, Wq, bq, Wk, Wv, Wg, q_ws);
  // 2) pair bias (LN folded)
  pair_bias_kernel<<<dim3((S * S) / 128), 128, 0, stream>>>(z, ln_w, ln_b, Wz, bias_ws);
  // 3) flash attention
  attn_kernel<<<dim3(H * (S / 64)), 256, 0, stream>>>(q_ws, k_ws, v_ws, bias_ws, o_ws);
  // 4) gate + output projection
  outproj_kernel<<<dim3(D / 64, S / 64), 256, 0, stream>>>(o_ws, g_ws, Wo, out);
}